// Round 7
// baseline (1359.677 us; speedup 1.0000x reference)
//
#include <hip/hip_runtime.h>
#include <hip/hip_bf16.h>

typedef __hip_bfloat16 bf16;
typedef unsigned short u16;
typedef __attribute__((ext_vector_type(8))) short bf16x8;   // 8 bf16 in 4 VGPRs (MFMA A/B frag)
typedef __attribute__((ext_vector_type(4))) float f32x4;    // MFMA C/D frag

#define N_NODES 100000
#define N_EDGES 1600000
#define NBUCK 391           // ceil(N_NODES/256), bucket = dst >> 8
#define NBLK 512            // edge-chunk blocks for hist/scatter (q1/q2/q4)

static __device__ __forceinline__ u16 f2bf(float x) {
    bf16 h = (bf16)x;
    return *reinterpret_cast<u16*>(&h);
}
static __device__ __forceinline__ float bf2f(u16 b) {
    unsigned u = ((unsigned)b) << 16;
    return __uint_as_float(u);
}

// ================= Weight pre-fragmentation (device fn, folded into q1) =================
// W' = [Ws | Wn] combined, [64 k][2*ncol n], split into bf16 hi/lo:
//   w = wh + wl  (3-pass GEMM ah@wh + al@wh + ah@wl -> f32-grade accuracy).

static __device__ void wprep_one(int id,
                                 const float* Ws0, const float* Wn0,
                                 const float* Ws1, const float* Wn1,
                                 const float* Ws2, const float* Wn2,
                                 u16* wf0, u16* wf1, u16* wf2) {
    const float *Ws, *Wn;
    u16* wf;
    int ncol, nfc;
    if (id < 4096)       { Ws = Ws0; Wn = Wn0; wf = wf0; ncol = 64; nfc = 8; }
    else if (id < 8192)  { id -= 4096; Ws = Ws1; Wn = Wn1; wf = wf1; ncol = 64; nfc = 8; }
    else if (id < 9216)  { id -= 8192; Ws = Ws2; Wn = Wn2; wf = wf2; ncol = 16; nfc = 2; }
    else return;
    int kp = id / (2 * ncol);       // 0..31 k-pair
    int n  = id % (2 * ncol);
    int k  = kp * 2;
    float w0 = (n < ncol) ? Ws[k * ncol + n]       : Wn[k * ncol + (n - ncol)];
    float w1 = (n < ncol) ? Ws[(k + 1) * ncol + n] : Wn[(k + 1) * ncol + (n - ncol)];
    u16 h0 = f2bf(w0), h1 = f2bf(w1);
    u16 l0 = f2bf(w0 - bf2f(h0)), l1 = f2bf(w1 - bf2f(h1));
    int ks = k >> 5, kg = (k >> 3) & 3, j = k & 7;          // j even
    int nf = n >> 4, nl = n & 15;
    int lane = kg * 16 + nl;
    int bhi = ((ks * nfc + nf) * 2 + 0) * 512 + lane * 8 + j;
    int blo = ((ks * nfc + nf) * 2 + 1) * 512 + lane * 8 + j;
    *(unsigned*)&wf[bhi] = (unsigned)h0 | ((unsigned)h1 << 16);
    *(unsigned*)&wf[blo] = (unsigned)l0 | ((unsigned)l1 << 16);
}

// ================= CSR build: deterministic bucket sort (round-5 proven shapes) =================
// Round-2: random 4B global scatter = 16x write amp. Round-4: per-edge conflicted
// LDS atomics ~250cyc. Round-6: radix-staged q4 + mfma 2-rowset = neutral/worse ->
// reverted to round-5 shapes everywhere.

__global__ __launch_bounds__(512) void q1_hist(const int* __restrict__ dst,
                                               int* __restrict__ bh, int nE,
                                               const float* __restrict__ Ws0, const float* __restrict__ Wn0,
                                               const float* __restrict__ Ws1, const float* __restrict__ Wn1,
                                               const float* __restrict__ Ws2, const float* __restrict__ Wn2,
                                               u16* __restrict__ wf0, u16* __restrict__ wf1,
                                               u16* __restrict__ wf2) {
    __shared__ int hist[NBUCK];
    int t = threadIdx.x, b = blockIdx.x;
    if (b < 36 && t < 256)   // folded weight prep (9216 ids)
        wprep_one(b * 256 + t, Ws0, Wn0, Ws1, Wn1, Ws2, Wn2, wf0, wf1, wf2);
    for (int i = t; i < NBUCK; i += 512) hist[i] = 0;
    __syncthreads();
    int chunk = (nE + NBLK - 1) / NBLK;
    int lo = b * chunk, hi = min(nE, lo + chunk);
    for (int e = lo + t; e < hi; e += 512) atomicAdd(&hist[dst[e] >> 8], 1);
    __syncthreads();
    for (int i = t; i < NBUCK; i += 512) bh[b * NBUCK + i] = hist[i];
}

__global__ __launch_bounds__(512) void q2_colscan(int* __restrict__ bh,
                                                  int* __restrict__ total) {
    __shared__ int s[512];
    int i = blockIdx.x;       // bucket
    int b = threadIdx.x;      // chunk-block
    int val = bh[b * NBUCK + i];
    s[b] = val;
    __syncthreads();
    for (int off = 1; off < 512; off <<= 1) {
        int x = (b >= off) ? s[b - off] : 0;
        __syncthreads();
        if (b >= off) s[b] += x;
        __syncthreads();
    }
    bh[b * NBUCK + i] = s[b] - val;        // exclusive over blocks
    if (b == 511) total[i] = s[511];
}

__global__ __launch_bounds__(512) void q3_scan(const int* __restrict__ total,
                                               int* __restrict__ bucket_base, int nE) {
    __shared__ int s[512];
    int t = threadIdx.x;
    int val = (t < NBUCK) ? total[t] : 0;
    s[t] = val;
    __syncthreads();
    for (int off = 1; off < 512; off <<= 1) {
        int x = (t >= off) ? s[t - off] : 0;
        __syncthreads();
        if (t >= off) s[t] += x;
        __syncthreads();
    }
    if (t < NBUCK) bucket_base[t] = s[t] - val;
    if (t == 0) bucket_base[NBUCK] = nE;
}

// ================= MFMA projection body (shared by fused + standalone) =================
// C[*,128] = h @ [Ws|Wn]; cols 0..63 -> outF f32 (+bias); cols 64..127 -> zbq,
// bf16-packed in 4 COLUMN-QUARTER arrays (32 B/node rows) so the gather can pin
// one 3.2 MB quarter per XCD L2 (this round's change).

template <bool RELU_IN>
static __device__ __forceinline__ void mfma128_body(int rowbase, int lane,
                                                    const float* __restrict__ h,
                                                    const u16* sW,
                                                    const float* __restrict__ bias,
                                                    float* __restrict__ outF,
                                                    unsigned* __restrict__ zbq) {
    int nl = lane & 15, kg = lane >> 4;
    int node = rowbase + nl;
    bool nv = node < N_NODES;
    const float* hp = h + (size_t)node * 64 + kg * 8;

    f32x4 acc[8];
#pragma unroll
    for (int i = 0; i < 8; ++i) acc[i] = (f32x4){0.f, 0.f, 0.f, 0.f};

#pragma unroll
    for (int ks = 0; ks < 2; ++ks) {
        float4 a0, a1;
        if (nv) {
            a0 = *(const float4*)(hp + ks * 32);
            a1 = *(const float4*)(hp + ks * 32 + 4);
        } else {
            a0 = make_float4(0.f, 0.f, 0.f, 0.f);
            a1 = a0;
        }
        float av[8] = {a0.x, a0.y, a0.z, a0.w, a1.x, a1.y, a1.z, a1.w};
        bf16x8 ah, al;
#pragma unroll
        for (int j = 0; j < 8; ++j) {
            float v = av[j];
            if (RELU_IN) v = fmaxf(v, 0.f);
            u16 hb = f2bf(v);
            ah[j] = (short)hb;
            al[j] = (short)f2bf(v - bf2f(hb));
        }
#pragma unroll
        for (int nf = 0; nf < 8; ++nf) {
            bf16x8 wh = *(const bf16x8*)&sW[((ks * 8 + nf) * 2 + 0) * 512 + lane * 8];
            bf16x8 wl = *(const bf16x8*)&sW[((ks * 8 + nf) * 2 + 1) * 512 + lane * 8];
            acc[nf] = __builtin_amdgcn_mfma_f32_16x16x32_bf16(ah, wh, acc[nf], 0, 0, 0);
            acc[nf] = __builtin_amdgcn_mfma_f32_16x16x32_bf16(al, wh, acc[nf], 0, 0, 0);
            acc[nf] = __builtin_amdgcn_mfma_f32_16x16x32_bf16(ah, wl, acc[nf], 0, 0, 0);
        }
    }

    // D layout: col = lane&15, row_in_frag = kg*4 + r  (m89-verified)
#pragma unroll
    for (int nf = 0; nf < 4; ++nf) {            // F half, f32 + bias
        int col = nf * 16 + nl;
        float b = bias[col];
#pragma unroll
        for (int r = 0; r < 4; ++r) {
            int row = rowbase + kg * 4 + r;
            if (row < N_NODES) outF[(size_t)row * 64 + col] = acc[nf][r] + b;
        }
    }
#pragma unroll
    for (int nf = 4; nf < 8; ++nf) {            // Z half -> quarter array nf-4
        int q = nf - 4;
#pragma unroll
        for (int r = 0; r < 4; ++r) {
            float v = acc[nf][r];
            float p = __shfl_xor(v, 1);         // partner col (nl^1), same row
            int row = rowbase + kg * 4 + r;
            if (!(nl & 1) && row < N_NODES)
                zbq[((size_t)q * N_NODES + row) * 8 + (nl >> 1)] =
                    (unsigned)f2bf(v) | ((unsigned)f2bf(p) << 16);
        }
    }
}

// ================= Fused q4_scatter + layer-1 MFMA =================
// mfma1 depends only on wprep+feat, q4 on q1..q3 -- independent. Same-stream
// kernels serialize, so fuse: blocks 0..511 run q4, 512..1293 run mfma1
// (8 waves x 16 rows = 128 rows/block). Memory-scatter waves and MFMA waves
// co-resident on the CUs (m114: separate pipes overlap).

__global__ __launch_bounds__(512) void f_q4m1(const int* __restrict__ src,
                                              const int* __restrict__ dst,
                                              const int* __restrict__ bh,
                                              const int* __restrict__ bucket_base,
                                              unsigned int* __restrict__ packed, int nE,
                                              const float* __restrict__ h,
                                              const u16* __restrict__ wf,
                                              const float* __restrict__ bias,
                                              float* __restrict__ outF,
                                              unsigned* __restrict__ zbq) {
    __shared__ uint4 smem4[2048];   // 32 KB union
    int t = threadIdx.x;
    if (blockIdx.x < NBLK) {
        // ---- q4 branch (round-5 verbatim) ----
        int* cur = (int*)smem4;
        int b = blockIdx.x;
        for (int i = t; i < NBUCK; i += 512)
            cur[i] = bucket_base[i] + bh[b * NBUCK + i];
        __syncthreads();
        int chunk = (nE + NBLK - 1) / NBLK;
        int lo = b * chunk, hi = min(nE, lo + chunk);
        for (int e = lo + t; e < hi; e += 512) {
            int d = dst[e];
            int pos = atomicAdd(&cur[d >> 8], 1);
            packed[pos] = ((unsigned int)(d & 255) << 17) | (unsigned int)src[e];
        }
    } else {
        // ---- layer-1 MFMA branch ----
        u16* sW = (u16*)smem4;
        const uint4* g = (const uint4*)wf;
#pragma unroll
        for (int i = 0; i < 8; ++i) smem4[t + i * 512] = g[t + i * 512];
        __syncthreads();
        int lane = t & 63, wid = t >> 6;
        int rowbase = (blockIdx.x - NBLK) * 128 + wid * 16;
        mfma128_body<false>(rowbase, lane, h, sW, bias, outF, zbq);
    }
}

__global__ __launch_bounds__(1024) void p4_build(const unsigned int* __restrict__ packed,
                                                 const int* __restrict__ bucket_base,
                                                 int* __restrict__ rowptr,
                                                 int* __restrict__ csr, int nN, int nE,
                                                 int* __restrict__ qc) {
    __shared__ int cnt[256];
    __shared__ int s[256];
    __shared__ int curs[256];
    int b = blockIdx.x;
    int t = threadIdx.x;
    if (b == 0 && t < 8) qc[t] = 0;       // zero gather work-queues (both layers)
    int node0 = b << 8;
    int ebase = bucket_base[b];
    int eend  = bucket_base[b + 1];

    if (t < 256) cnt[t] = 0;
    __syncthreads();
    for (int e = ebase + t; e < eend; e += 1024)
        atomicAdd(&cnt[packed[e] >> 17], 1);
    __syncthreads();
    int val = (t < 256) ? cnt[t] : 0;
    if (t < 256) s[t] = val;
    __syncthreads();
    for (int off = 1; off < 256; off <<= 1) {
        int x = (t < 256 && t >= off) ? s[t - off] : 0;
        __syncthreads();
        if (t < 256 && t >= off) s[t] += x;
        __syncthreads();
    }
    if (t < 256) {
        int excl = s[t] - val;
        int node = node0 + t;
        if (node < nN) rowptr[node] = ebase + excl;
        curs[t] = ebase + excl;
    }
    if (b == gridDim.x - 1 && t == 0) rowptr[nN] = nE;
    __syncthreads();
    for (int e = ebase + t; e < eend; e += 1024) {
        unsigned int p = packed[e];
        int d = p >> 17;
        int pos = atomicAdd(&curs[d], 1);
        csr[pos] = (int)(p & 0x1FFFFu);
    }
}

// ================= Standalone MFMA GEMM (layer 2) =================

template <bool RELU_IN>
__global__ __launch_bounds__(256) void k_mfma128s(const float* __restrict__ h,
                                                  const u16* __restrict__ wf,
                                                  const float* __restrict__ bias,
                                                  float* __restrict__ outF,
                                                  unsigned* __restrict__ zbq) {
    __shared__ u16 sW[16384];   // 32 KB
    int t = threadIdx.x;
    {
        const uint4* g = (const uint4*)wf;
        uint4* s = (uint4*)sW;
#pragma unroll
        for (int i = 0; i < 8; ++i) s[t + i * 256] = g[t + i * 256];
    }
    __syncthreads();
    int lane = t & 63, wid = t >> 6;
    mfma128_body<RELU_IN>(blockIdx.x * 64 + wid * 16, lane, h, sW, bias, outF, zbq);
}

// ================= MFMA projection, layer 3 (round-5 verbatim) =================

__global__ __launch_bounds__(256) void k_mfma32(const float* __restrict__ h,
                                                const u16* __restrict__ wf,
                                                const float* __restrict__ bias,
                                                float* __restrict__ wbuf,
                                                float* __restrict__ zbuf) {
    __shared__ u16 sW[4096];    // 8 KB
    int t = threadIdx.x;
    {
        const uint4* g = (const uint4*)wf;
        uint4* s = (uint4*)sW;
        s[t] = g[t];
        s[t + 256] = g[t + 256];
    }
    __syncthreads();

    int lane = t & 63, wid = t >> 6;
    int nl = lane & 15, kg = lane >> 4;
    int rowbase = blockIdx.x * 64 + wid * 16;
    int node = rowbase + nl;
    bool nv = node < N_NODES;
    const float* hp = h + (size_t)node * 64 + kg * 8;

    f32x4 acc[2];
    acc[0] = (f32x4){0.f, 0.f, 0.f, 0.f};
    acc[1] = acc[0];

#pragma unroll
    for (int ks = 0; ks < 2; ++ks) {
        float4 a0, a1;
        if (nv) {
            a0 = *(const float4*)(hp + ks * 32);
            a1 = *(const float4*)(hp + ks * 32 + 4);
        } else {
            a0 = make_float4(0.f, 0.f, 0.f, 0.f);
            a1 = a0;
        }
        float av[8] = {a0.x, a0.y, a0.z, a0.w, a1.x, a1.y, a1.z, a1.w};
        bf16x8 ah, al;
#pragma unroll
        for (int j = 0; j < 8; ++j) {
            float v = fmaxf(av[j], 0.f);        // layer-3 input is relu(h2)
            u16 hb = f2bf(v);
            ah[j] = (short)hb;
            al[j] = (short)f2bf(v - bf2f(hb));
        }
#pragma unroll
        for (int nf = 0; nf < 2; ++nf) {
            bf16x8 wh = *(const bf16x8*)&sW[((ks * 2 + nf) * 2 + 0) * 512 + lane * 8];
            bf16x8 wl = *(const bf16x8*)&sW[((ks * 2 + nf) * 2 + 1) * 512 + lane * 8];
            acc[nf] = __builtin_amdgcn_mfma_f32_16x16x32_bf16(ah, wh, acc[nf], 0, 0, 0);
            acc[nf] = __builtin_amdgcn_mfma_f32_16x16x32_bf16(al, wh, acc[nf], 0, 0, 0);
            acc[nf] = __builtin_amdgcn_mfma_f32_16x16x32_bf16(ah, wl, acc[nf], 0, 0, 0);
        }
    }

    float b = bias[nl];
#pragma unroll
    for (int r = 0; r < 4; ++r) {
        int row = rowbase + kg * 4 + r;
        if (row < N_NODES) {
            wbuf[(size_t)row * 16 + nl] = acc[0][r] + b;   // self + bias
            zbuf[(size_t)row * 16 + nl] = acc[1][r];       // neigh projection
        }
    }
}

// ================= XCD-pinned quarter gather (layers 1/2) =================
// z stored as 4 column-quarter arrays (3.2 MB each, 32 B/node). Each block reads
// its REAL XCD id (s_getreg HW_REG_XCC_ID, m09-verified) and serves quarter
// xcc>>1 -> that XCD's L2 working set = one 3.2 MB quarter (< 4 MB) -> z reads
// become L2 hits instead of 31%-hit L3 traffic. Per-quarter atomic work queues
// (device-scope, zeroed in p4) make coverage correct for ANY block->XCD
// distribution; after its own quarter drains, a block steals from the others.
// 8 edges per wave-load (8 lanes x 32 B each); register accumulation (round-4
// lesson: no per-edge LDS atomics).

__global__ __launch_bounds__(256, 8) void k_gatherq(const int* __restrict__ rowptr,
                                                    const int* __restrict__ csr,
                                                    const unsigned* __restrict__ zbq,
                                                    float* __restrict__ out,
                                                    int* __restrict__ qc) {
    int t = threadIdx.x;
    int lane = t & 63;
    int sub = lane >> 3, f = lane & 7;

    unsigned xcc;
    asm volatile("s_getreg_b32 %0, hwreg(HW_REG_XCC_ID)" : "=s"(xcc));
    int q0 = (int)((xcc >> 1) & 3);

    for (int dq = 0; dq < 4; ++dq) {
        int q = (q0 + dq) & 3;
        const unsigned* zq = zbq + (size_t)q * N_NODES * 8;
        for (;;) {
            int c = 0;
            if (lane == 0) c = atomicAdd(&qc[q], 1);
            c = __shfl(c, 0);
            int v0 = c * 32;
            if (v0 >= N_NODES) break;
            int vend = min(v0 + 32, N_NODES);
            for (int v = v0; v < vend; ++v) {
                int beg = rowptr[v];
                int end = rowptr[v + 1];
                float ax = 0.f, ay = 0.f;
                for (int e0 = beg; e0 < end; e0 += 64) {
                    int n = end - e0; if (n > 64) n = 64;
                    int ids = (e0 + lane < end) ? csr[e0 + lane] : 0;
                    int ng = n >> 3;
                    int g = 0;
                    for (; g + 2 <= ng; g += 2) {
                        int r0 = __shfl(ids, g * 8 + sub);
                        int r1 = __shfl(ids, g * 8 + 8 + sub);
                        unsigned d0 = zq[(size_t)r0 * 8 + f];
                        unsigned d1 = zq[(size_t)r1 * 8 + f];
                        ax += __uint_as_float(d0 << 16); ay += __uint_as_float(d0 & 0xffff0000u);
                        ax += __uint_as_float(d1 << 16); ay += __uint_as_float(d1 & 0xffff0000u);
                    }
                    for (; g < ng; ++g) {
                        int r = __shfl(ids, g * 8 + sub);
                        unsigned d = zq[(size_t)r * 8 + f];
                        ax += __uint_as_float(d << 16); ay += __uint_as_float(d & 0xffff0000u);
                    }
                    int rem = n & 7;
                    if (rem) {
                        int e = ng * 8 + sub;
                        int r = __shfl(ids, (e < n) ? e : (n - 1));
                        if (e < n) {
                            unsigned d = zq[(size_t)r * 8 + f];
                            ax += __uint_as_float(d << 16); ay += __uint_as_float(d & 0xffff0000u);
                        }
                    }
                }
                ax += __shfl_xor(ax, 8);  ay += __shfl_xor(ay, 8);
                ax += __shfl_xor(ax, 16); ay += __shfl_xor(ay, 16);
                ax += __shfl_xor(ax, 32); ay += __shfl_xor(ay, 32);
                if (sub == 0) {
                    float inv = 1.f / fmaxf((float)(end - beg), 1.f);
                    float2* op = (float2*)(out + (size_t)v * 64 + q * 16) + f;
                    float2 cur = *op;
                    cur.x += ax * inv;
                    cur.y += ay * inv;
                    *op = cur;
                }
            }
        }
    }
}

// ===== Layer-3 gather (round-5 verbatim) =====

__global__ __launch_bounds__(256, 8) void k_gather3(const int* __restrict__ rowptr,
                                                    const int* __restrict__ csr,
                                                    const float* __restrict__ zbuf,
                                                    const float* __restrict__ wbuf,
                                                    float* __restrict__ out) {
    int t = threadIdx.x;
    int w = t >> 6;
    int lane = t & 63;
    int g = lane >> 4;
    int j = lane & 15;

    for (int v = blockIdx.x * 4 + w; v < N_NODES; v += gridDim.x * 4) {
        int beg = rowptr[v];
        int end = rowptr[v + 1];
        float acc = 0.f;
        int e = beg + g;
        for (; e + 4 < end; e += 8) {
            float a0 = zbuf[(size_t)csr[e] * 16 + j];
            float a1 = zbuf[(size_t)csr[e + 4] * 16 + j];
            acc += a0;
            acc += a1;
        }
        if (e < end) acc += zbuf[(size_t)csr[e] * 16 + j];
        acc += __shfl_xor(acc, 16);
        acc += __shfl_xor(acc, 32);
        if (g == 0) {
            float deg = (float)(end - beg);
            out[(size_t)v * 16 + j] = wbuf[(size_t)v * 16 + j] + acc / fmaxf(deg, 1.0f);
        }
    }
}

// ---------------- launch ----------------

extern "C" void kernel_launch(void* const* d_in, const int* in_sizes, int n_in,
                              void* d_out, int out_size, void* d_ws, size_t ws_size,
                              hipStream_t stream) {
    const float* feat = (const float*)d_in[0];
    const int* ei = (const int*)d_in[1];
    const int* src = ei;
    const int* dst = ei + N_EDGES;
    const float* Ws0 = (const float*)d_in[2];
    const float* Wn0 = (const float*)d_in[3];
    const float* b0  = (const float*)d_in[4];
    const float* Ws1 = (const float*)d_in[5];
    const float* Wn1 = (const float*)d_in[6];
    const float* b1  = (const float*)d_in[7];
    const float* Ws2 = (const float*)d_in[8];
    const float* Wn2 = (const float*)d_in[9];
    const float* b2  = (const float*)d_in[10];

    float* out = (float*)d_out;
    float* out_h3 = out;                                 // [N,16]
    float* out_e0 = out + (size_t)N_NODES * 16;          // [N,64]  pre-relu h1
    float* out_e1 = out + (size_t)N_NODES * (16 + 64);   // [N,64]  pre-relu h2

    char* ws = (char*)d_ws;
    size_t off = 0;
    auto alloc = [&](size_t bytes) -> void* {
        void* p = ws + off;
        off = (off + bytes + 255) & ~(size_t)255;
        return p;
    };
    int* bh          = (int*)alloc((size_t)NBLK * NBUCK * sizeof(int));   // 800 KB
    int* total       = (int*)alloc(NBUCK * sizeof(int));
    int* bucket_base = (int*)alloc((NBUCK + 1) * sizeof(int));
    int* rowptr      = (int*)alloc((N_NODES + 1) * sizeof(int));
    unsigned int* packed = (unsigned int*)alloc(N_EDGES * sizeof(int));   // 6.4 MB
    int* csr         = (int*)alloc(N_EDGES * sizeof(int));                // 6.4 MB
    unsigned* zbq    = (unsigned*)alloc((size_t)4 * N_NODES * 8 * sizeof(unsigned)); // 12.8 MB (4 quarters)
    u16* wf0         = (u16*)alloc(16384 * sizeof(u16));  // layer-1 W frags hi/lo (32 KB)
    u16* wf1         = (u16*)alloc(16384 * sizeof(u16));  // layer-2
    u16* wf2         = (u16*)alloc(4096 * sizeof(u16));   // layer-3 (8 KB)
    int* qc          = (int*)alloc(8 * sizeof(int));      // gather work-queues (2 layers x 4 quarters)
    // layer-3 z (f32 [N,16] = 6.4 MB) aliases `packed` (dead after p4_build)
    float* zbuf3     = (float*)packed;
    (void)ws_size;

    q1_hist<<<NBLK, 512, 0, stream>>>(dst, bh, N_EDGES,
                                      Ws0, Wn0, Ws1, Wn1, Ws2, Wn2, wf0, wf1, wf2);
    q2_colscan<<<NBUCK, 512, 0, stream>>>(bh, total);
    q3_scan<<<1, 512, 0, stream>>>(total, bucket_base, N_EDGES);
    // fused: q4 scatter (blocks 0..511) + layer-1 MFMA (blocks 512..1293)
    f_q4m1<<<NBLK + 782, 512, 0, stream>>>(src, dst, bh, bucket_base, packed, N_EDGES,
                                           feat, wf0, b0, out_e0, zbq);
    p4_build<<<NBUCK, 1024, 0, stream>>>(packed, bucket_base, rowptr, csr,
                                         N_NODES, N_EDGES, qc);

    // layer 1 gather
    k_gatherq<<<2048, 256, 0, stream>>>(rowptr, csr, zbq, out_e0, qc);
    // layer 2
    k_mfma128s<true><<<(N_NODES + 63) / 64, 256, 0, stream>>>(out_e0, wf1, b1, out_e1, zbq);
    k_gatherq<<<2048, 256, 0, stream>>>(rowptr, csr, zbq, out_e1, qc + 4);
    // layer 3
    k_mfma32<<<(N_NODES + 63) / 64, 256, 0, stream>>>(out_e1, wf2, b2, out_h3, zbuf3);
    k_gather3<<<2048, 256, 0, stream>>>(rowptr, csr, zbuf3, out_h3, out_h3);
}

// Round 8
// 295.843 us; speedup vs baseline: 4.5959x; 4.5959x over previous
//
#include <hip/hip_runtime.h>
#include <hip/hip_bf16.h>

typedef __hip_bfloat16 bf16;
typedef unsigned short u16;
typedef __attribute__((ext_vector_type(8))) short bf16x8;   // 8 bf16 in 4 VGPRs (MFMA A/B frag)
typedef __attribute__((ext_vector_type(4))) float f32x4;    // MFMA C/D frag

#define N_NODES 100000
#define N_EDGES 1600000
#define NBUCK 391           // ceil(N_NODES/256), bucket = dst >> 8
#define NBLK 512            // edge-chunk blocks for hist/scatter (q1/q2/q4)

static __device__ __forceinline__ u16 f2bf(float x) {
    bf16 h = (bf16)x;
    return *reinterpret_cast<u16*>(&h);
}
static __device__ __forceinline__ float bf2f(u16 b) {
    unsigned u = ((unsigned)b) << 16;
    return __uint_as_float(u);
}

// ================= Weight pre-fragmentation (device fn, folded into q1) =================
// W' = [Ws | Wn] combined, [64 k][2*ncol n], split into bf16 hi/lo:
//   w = wh + wl  (3-pass GEMM ah@wh + al@wh + ah@wl -> f32-grade accuracy).

static __device__ void wprep_one(int id,
                                 const float* Ws0, const float* Wn0,
                                 const float* Ws1, const float* Wn1,
                                 const float* Ws2, const float* Wn2,
                                 u16* wf0, u16* wf1, u16* wf2) {
    const float *Ws, *Wn;
    u16* wf;
    int ncol, nfc;
    if (id < 4096)       { Ws = Ws0; Wn = Wn0; wf = wf0; ncol = 64; nfc = 8; }
    else if (id < 8192)  { id -= 4096; Ws = Ws1; Wn = Wn1; wf = wf1; ncol = 64; nfc = 8; }
    else if (id < 9216)  { id -= 8192; Ws = Ws2; Wn = Wn2; wf = wf2; ncol = 16; nfc = 2; }
    else return;
    int kp = id / (2 * ncol);       // 0..31 k-pair
    int n  = id % (2 * ncol);
    int k  = kp * 2;
    float w0 = (n < ncol) ? Ws[k * ncol + n]       : Wn[k * ncol + (n - ncol)];
    float w1 = (n < ncol) ? Ws[(k + 1) * ncol + n] : Wn[(k + 1) * ncol + (n - ncol)];
    u16 h0 = f2bf(w0), h1 = f2bf(w1);
    u16 l0 = f2bf(w0 - bf2f(h0)), l1 = f2bf(w1 - bf2f(h1));
    int ks = k >> 5, kg = (k >> 3) & 3, j = k & 7;          // j even
    int nf = n >> 4, nl = n & 15;
    int lane = kg * 16 + nl;
    int bhi = ((ks * nfc + nf) * 2 + 0) * 512 + lane * 8 + j;
    int blo = ((ks * nfc + nf) * 2 + 1) * 512 + lane * 8 + j;
    *(unsigned*)&wf[bhi] = (unsigned)h0 | ((unsigned)h1 << 16);
    *(unsigned*)&wf[blo] = (unsigned)l0 | ((unsigned)l1 << 16);
}

// ================= CSR build: deterministic bucket sort (round-5 proven shapes) =================
// Round-2: random 4B global scatter = 16x write amp. Round-4: per-edge conflicted
// LDS atomics ~250cyc. Round-7: 32B quarter-row gather = half-line reads + L2
// thrash (FETCH 76MB, 595us) -> gather must read full 128B rows. Keep the
// round-7 WIN: q4+mfma1 fusion and wprep folded into q1 (~45us saved).

__global__ __launch_bounds__(512) void q1_hist(const int* __restrict__ dst,
                                               int* __restrict__ bh, int nE,
                                               const float* __restrict__ Ws0, const float* __restrict__ Wn0,
                                               const float* __restrict__ Ws1, const float* __restrict__ Wn1,
                                               const float* __restrict__ Ws2, const float* __restrict__ Wn2,
                                               u16* __restrict__ wf0, u16* __restrict__ wf1,
                                               u16* __restrict__ wf2) {
    __shared__ int hist[NBUCK];
    int t = threadIdx.x, b = blockIdx.x;
    if (b < 36 && t < 256)   // folded weight prep (9216 ids)
        wprep_one(b * 256 + t, Ws0, Wn0, Ws1, Wn1, Ws2, Wn2, wf0, wf1, wf2);
    for (int i = t; i < NBUCK; i += 512) hist[i] = 0;
    __syncthreads();
    int chunk = (nE + NBLK - 1) / NBLK;
    int lo = b * chunk, hi = min(nE, lo + chunk);
    for (int e = lo + t; e < hi; e += 512) atomicAdd(&hist[dst[e] >> 8], 1);
    __syncthreads();
    for (int i = t; i < NBUCK; i += 512) bh[b * NBUCK + i] = hist[i];
}

__global__ __launch_bounds__(512) void q2_colscan(int* __restrict__ bh,
                                                  int* __restrict__ total) {
    __shared__ int s[512];
    int i = blockIdx.x;       // bucket
    int b = threadIdx.x;      // chunk-block
    int val = bh[b * NBUCK + i];
    s[b] = val;
    __syncthreads();
    for (int off = 1; off < 512; off <<= 1) {
        int x = (b >= off) ? s[b - off] : 0;
        __syncthreads();
        if (b >= off) s[b] += x;
        __syncthreads();
    }
    bh[b * NBUCK + i] = s[b] - val;        // exclusive over blocks
    if (b == 511) total[i] = s[511];
}

__global__ __launch_bounds__(512) void q3_scan(const int* __restrict__ total,
                                               int* __restrict__ bucket_base, int nE) {
    __shared__ int s[512];
    int t = threadIdx.x;
    int val = (t < NBUCK) ? total[t] : 0;
    s[t] = val;
    __syncthreads();
    for (int off = 1; off < 512; off <<= 1) {
        int x = (t >= off) ? s[t - off] : 0;
        __syncthreads();
        if (t >= off) s[t] += x;
        __syncthreads();
    }
    if (t < NBUCK) bucket_base[t] = s[t] - val;
    if (t == 0) bucket_base[NBUCK] = nE;
}

// ================= MFMA projection body (shared by fused + standalone) =================
// C[*,128] = h @ [Ws|Wn]; cols 0..63 -> outF f32 (+bias); cols 64..127 -> outZ,
// bf16-packed contiguous 128B rows (round-5 layout: gather reads full lines).

template <bool RELU_IN>
static __device__ __forceinline__ void mfma128_body(int rowbase, int lane,
                                                    const float* __restrict__ h,
                                                    const u16* sW,
                                                    const float* __restrict__ bias,
                                                    float* __restrict__ outF,
                                                    unsigned* __restrict__ outZ) {
    int nl = lane & 15, kg = lane >> 4;
    int node = rowbase + nl;
    bool nv = node < N_NODES;
    const float* hp = h + (size_t)node * 64 + kg * 8;

    f32x4 acc[8];
#pragma unroll
    for (int i = 0; i < 8; ++i) acc[i] = (f32x4){0.f, 0.f, 0.f, 0.f};

#pragma unroll
    for (int ks = 0; ks < 2; ++ks) {
        float4 a0, a1;
        if (nv) {
            a0 = *(const float4*)(hp + ks * 32);
            a1 = *(const float4*)(hp + ks * 32 + 4);
        } else {
            a0 = make_float4(0.f, 0.f, 0.f, 0.f);
            a1 = a0;
        }
        float av[8] = {a0.x, a0.y, a0.z, a0.w, a1.x, a1.y, a1.z, a1.w};
        bf16x8 ah, al;
#pragma unroll
        for (int j = 0; j < 8; ++j) {
            float v = av[j];
            if (RELU_IN) v = fmaxf(v, 0.f);
            u16 hb = f2bf(v);
            ah[j] = (short)hb;
            al[j] = (short)f2bf(v - bf2f(hb));
        }
#pragma unroll
        for (int nf = 0; nf < 8; ++nf) {
            bf16x8 wh = *(const bf16x8*)&sW[((ks * 8 + nf) * 2 + 0) * 512 + lane * 8];
            bf16x8 wl = *(const bf16x8*)&sW[((ks * 8 + nf) * 2 + 1) * 512 + lane * 8];
            acc[nf] = __builtin_amdgcn_mfma_f32_16x16x32_bf16(ah, wh, acc[nf], 0, 0, 0);
            acc[nf] = __builtin_amdgcn_mfma_f32_16x16x32_bf16(al, wh, acc[nf], 0, 0, 0);
            acc[nf] = __builtin_amdgcn_mfma_f32_16x16x32_bf16(ah, wl, acc[nf], 0, 0, 0);
        }
    }

    // D layout: col = lane&15, row_in_frag = kg*4 + r  (m89-verified)
#pragma unroll
    for (int nf = 0; nf < 4; ++nf) {            // F half, f32 + bias
        int col = nf * 16 + nl;
        float b = bias[col];
#pragma unroll
        for (int r = 0; r < 4; ++r) {
            int row = rowbase + kg * 4 + r;
            if (row < N_NODES) outF[(size_t)row * 64 + col] = acc[nf][r] + b;
        }
    }
#pragma unroll
    for (int nf = 4; nf < 8; ++nf) {            // Z half, pack bf16 pairs via shfl
        int zc = nf * 16 + nl - 64;
#pragma unroll
        for (int r = 0; r < 4; ++r) {
            float v = acc[nf][r];
            float p = __shfl_xor(v, 1);         // partner col (nl^1), same row
            int row = rowbase + kg * 4 + r;
            if (!(nl & 1) && row < N_NODES)
                outZ[(size_t)row * 32 + (zc >> 1)] = (unsigned)f2bf(v) | ((unsigned)f2bf(p) << 16);
        }
    }
}

// ================= Fused q4_scatter + layer-1 MFMA =================
// mfma1 depends only on wprep+feat, q4 on q1..q3 -- independent. Same-stream
// kernels serialize, so fuse: blocks 0..511 run q4, 512..1293 run mfma1
// (8 waves x 16 rows = 128 rows/block). Memory-scatter waves and MFMA waves
// co-resident on the CUs (m114: separate pipes overlap).

__global__ __launch_bounds__(512) void f_q4m1(const int* __restrict__ src,
                                              const int* __restrict__ dst,
                                              const int* __restrict__ bh,
                                              const int* __restrict__ bucket_base,
                                              unsigned int* __restrict__ packed, int nE,
                                              const float* __restrict__ h,
                                              const u16* __restrict__ wf,
                                              const float* __restrict__ bias,
                                              float* __restrict__ outF,
                                              unsigned* __restrict__ outZ) {
    __shared__ uint4 smem4[2048];   // 32 KB union
    int t = threadIdx.x;
    if (blockIdx.x < NBLK) {
        // ---- q4 branch (round-5 verbatim) ----
        int* cur = (int*)smem4;
        int b = blockIdx.x;
        for (int i = t; i < NBUCK; i += 512)
            cur[i] = bucket_base[i] + bh[b * NBUCK + i];
        __syncthreads();
        int chunk = (nE + NBLK - 1) / NBLK;
        int lo = b * chunk, hi = min(nE, lo + chunk);
        for (int e = lo + t; e < hi; e += 512) {
            int d = dst[e];
            int pos = atomicAdd(&cur[d >> 8], 1);
            packed[pos] = ((unsigned int)(d & 255) << 17) | (unsigned int)src[e];
        }
    } else {
        // ---- layer-1 MFMA branch ----
        u16* sW = (u16*)smem4;
        const uint4* g = (const uint4*)wf;
#pragma unroll
        for (int i = 0; i < 4; ++i)             // 4 x 512 x 16B = 32 KB (r7 bug: was 8)
            smem4[t + i * 512] = g[t + i * 512];
        __syncthreads();
        int lane = t & 63, wid = t >> 6;
        int rowbase = (blockIdx.x - NBLK) * 128 + wid * 16;
        mfma128_body<false>(rowbase, lane, h, sW, bias, outF, outZ);
    }
}

__global__ __launch_bounds__(1024) void p4_build(const unsigned int* __restrict__ packed,
                                                 const int* __restrict__ bucket_base,
                                                 int* __restrict__ rowptr,
                                                 int* __restrict__ csr, int nN, int nE) {
    __shared__ int cnt[256];
    __shared__ int s[256];
    __shared__ int curs[256];
    int b = blockIdx.x;
    int t = threadIdx.x;
    int node0 = b << 8;
    int ebase = bucket_base[b];
    int eend  = bucket_base[b + 1];

    if (t < 256) cnt[t] = 0;
    __syncthreads();
    for (int e = ebase + t; e < eend; e += 1024)
        atomicAdd(&cnt[packed[e] >> 17], 1);
    __syncthreads();
    int val = (t < 256) ? cnt[t] : 0;
    if (t < 256) s[t] = val;
    __syncthreads();
    for (int off = 1; off < 256; off <<= 1) {
        int x = (t < 256 && t >= off) ? s[t - off] : 0;
        __syncthreads();
        if (t < 256 && t >= off) s[t] += x;
        __syncthreads();
    }
    if (t < 256) {
        int excl = s[t] - val;
        int node = node0 + t;
        if (node < nN) rowptr[node] = ebase + excl;
        curs[t] = ebase + excl;
    }
    if (b == gridDim.x - 1 && t == 0) rowptr[nN] = nE;
    __syncthreads();
    for (int e = ebase + t; e < eend; e += 1024) {
        unsigned int p = packed[e];
        int d = p >> 17;
        int pos = atomicAdd(&curs[d], 1);
        csr[pos] = (int)(p & 0x1FFFFu);
    }
}

// ================= Standalone MFMA GEMM (layer 2) =================

template <bool RELU_IN>
__global__ __launch_bounds__(256) void k_mfma128s(const float* __restrict__ h,
                                                  const u16* __restrict__ wf,
                                                  const float* __restrict__ bias,
                                                  float* __restrict__ outF,
                                                  unsigned* __restrict__ outZ) {
    __shared__ u16 sW[16384];   // 32 KB
    int t = threadIdx.x;
    {
        const uint4* g = (const uint4*)wf;
        uint4* s = (uint4*)sW;
#pragma unroll
        for (int i = 0; i < 8; ++i) s[t + i * 256] = g[t + i * 256];
    }
    __syncthreads();
    int lane = t & 63, wid = t >> 6;
    mfma128_body<RELU_IN>(blockIdx.x * 64 + wid * 16, lane, h, sW, bias, outF, outZ);
}

// ================= MFMA projection, layer 3 (round-5 verbatim) =================

__global__ __launch_bounds__(256) void k_mfma32(const float* __restrict__ h,
                                                const u16* __restrict__ wf,
                                                const float* __restrict__ bias,
                                                float* __restrict__ wbuf,
                                                float* __restrict__ zbuf) {
    __shared__ u16 sW[4096];    // 8 KB
    int t = threadIdx.x;
    {
        const uint4* g = (const uint4*)wf;
        uint4* s = (uint4*)sW;
        s[t] = g[t];
        s[t + 256] = g[t + 256];
    }
    __syncthreads();

    int lane = t & 63, wid = t >> 6;
    int nl = lane & 15, kg = lane >> 4;
    int rowbase = blockIdx.x * 64 + wid * 16;
    int node = rowbase + nl;
    bool nv = node < N_NODES;
    const float* hp = h + (size_t)node * 64 + kg * 8;

    f32x4 acc[2];
    acc[0] = (f32x4){0.f, 0.f, 0.f, 0.f};
    acc[1] = acc[0];

#pragma unroll
    for (int ks = 0; ks < 2; ++ks) {
        float4 a0, a1;
        if (nv) {
            a0 = *(const float4*)(hp + ks * 32);
            a1 = *(const float4*)(hp + ks * 32 + 4);
        } else {
            a0 = make_float4(0.f, 0.f, 0.f, 0.f);
            a1 = a0;
        }
        float av[8] = {a0.x, a0.y, a0.z, a0.w, a1.x, a1.y, a1.z, a1.w};
        bf16x8 ah, al;
#pragma unroll
        for (int j = 0; j < 8; ++j) {
            float v = fmaxf(av[j], 0.f);        // layer-3 input is relu(h2)
            u16 hb = f2bf(v);
            ah[j] = (short)hb;
            al[j] = (short)f2bf(v - bf2f(hb));
        }
#pragma unroll
        for (int nf = 0; nf < 2; ++nf) {
            bf16x8 wh = *(const bf16x8*)&sW[((ks * 2 + nf) * 2 + 0) * 512 + lane * 8];
            bf16x8 wl = *(const bf16x8*)&sW[((ks * 2 + nf) * 2 + 1) * 512 + lane * 8];
            acc[nf] = __builtin_amdgcn_mfma_f32_16x16x32_bf16(ah, wh, acc[nf], 0, 0, 0);
            acc[nf] = __builtin_amdgcn_mfma_f32_16x16x32_bf16(al, wh, acc[nf], 0, 0, 0);
            acc[nf] = __builtin_amdgcn_mfma_f32_16x16x32_bf16(ah, wl, acc[nf], 0, 0, 0);
        }
    }

    float b = bias[nl];
#pragma unroll
    for (int r = 0; r < 4; ++r) {
        int row = rowbase + kg * 4 + r;
        if (row < N_NODES) {
            wbuf[(size_t)row * 16 + nl] = acc[0][r] + b;   // self + bias
            zbuf[(size_t)row * 16 + nl] = acc[1][r];       // neigh projection
        }
    }
}

// ===== Gather (layers 1/2, bf16 z): out[v] += segmean(z[src]) =====
// Round-5 proven: CSR-walk, wave per node, 2 edges x 128B full-line reads per
// wave-load, register accumulation.

__global__ __launch_bounds__(256, 8) void k_gather64b(const int* __restrict__ rowptr,
                                                      const int* __restrict__ csr,
                                                      const unsigned int* __restrict__ z,
                                                      float* __restrict__ out) {
    int t = threadIdx.x;
    int w = t >> 6, lane = t & 63;
    int sub = lane >> 5;
    int f = lane & 31;

    for (int v = blockIdx.x * 4 + w; v < N_NODES; v += gridDim.x * 4) {
        int beg = rowptr[v];
        int end = rowptr[v + 1];
        float ax = 0.f, ay = 0.f;

        for (int e0 = beg; e0 < end; e0 += 64) {
            int n = end - e0; if (n > 64) n = 64;
            int ids = (e0 + lane < end) ? csr[e0 + lane] : 0;
            int full = n >> 1;
            int i = 0;
            for (; i + 4 <= full; i += 4) {
                int r0 = __shfl(ids, 2 * i + sub);
                int r1 = __shfl(ids, 2 * i + 2 + sub);
                int r2 = __shfl(ids, 2 * i + 4 + sub);
                int r3 = __shfl(ids, 2 * i + 6 + sub);
                unsigned d0 = z[(size_t)r0 * 32 + f];
                unsigned d1 = z[(size_t)r1 * 32 + f];
                unsigned d2 = z[(size_t)r2 * 32 + f];
                unsigned d3 = z[(size_t)r3 * 32 + f];
                ax += __uint_as_float(d0 << 16); ay += __uint_as_float(d0 & 0xffff0000u);
                ax += __uint_as_float(d1 << 16); ay += __uint_as_float(d1 & 0xffff0000u);
                ax += __uint_as_float(d2 << 16); ay += __uint_as_float(d2 & 0xffff0000u);
                ax += __uint_as_float(d3 << 16); ay += __uint_as_float(d3 & 0xffff0000u);
            }
            for (; i < full; ++i) {
                int r = __shfl(ids, 2 * i + sub);
                unsigned d = z[(size_t)r * 32 + f];
                ax += __uint_as_float(d << 16); ay += __uint_as_float(d & 0xffff0000u);
            }
            int rt = __shfl(ids, n - 1);
            if ((n & 1) && sub == 0) {
                unsigned d = z[(size_t)rt * 32 + f];
                ax += __uint_as_float(d << 16); ay += __uint_as_float(d & 0xffff0000u);
            }
        }

        ax += __shfl_xor(ax, 32);
        ay += __shfl_xor(ay, 32);
        if (sub == 0) {
            float inv = 1.f / fmaxf((float)(end - beg), 1.f);
            float2* op = (float2*)(out + (size_t)v * 64) + f;
            float2 cur = *op;
            cur.x += ax * inv;
            cur.y += ay * inv;
            *op = cur;
        }
    }
}

// ===== Layer-3 gather (round-5 verbatim) =====

__global__ __launch_bounds__(256, 8) void k_gather3(const int* __restrict__ rowptr,
                                                    const int* __restrict__ csr,
                                                    const float* __restrict__ zbuf,
                                                    const float* __restrict__ wbuf,
                                                    float* __restrict__ out) {
    int t = threadIdx.x;
    int w = t >> 6;
    int lane = t & 63;
    int g = lane >> 4;
    int j = lane & 15;

    for (int v = blockIdx.x * 4 + w; v < N_NODES; v += gridDim.x * 4) {
        int beg = rowptr[v];
        int end = rowptr[v + 1];
        float acc = 0.f;
        int e = beg + g;
        for (; e + 4 < end; e += 8) {
            float a0 = zbuf[(size_t)csr[e] * 16 + j];
            float a1 = zbuf[(size_t)csr[e + 4] * 16 + j];
            acc += a0;
            acc += a1;
        }
        if (e < end) acc += zbuf[(size_t)csr[e] * 16 + j];
        acc += __shfl_xor(acc, 16);
        acc += __shfl_xor(acc, 32);
        if (g == 0) {
            float deg = (float)(end - beg);
            out[(size_t)v * 16 + j] = wbuf[(size_t)v * 16 + j] + acc / fmaxf(deg, 1.0f);
        }
    }
}

// ---------------- launch ----------------

extern "C" void kernel_launch(void* const* d_in, const int* in_sizes, int n_in,
                              void* d_out, int out_size, void* d_ws, size_t ws_size,
                              hipStream_t stream) {
    const float* feat = (const float*)d_in[0];
    const int* ei = (const int*)d_in[1];
    const int* src = ei;
    const int* dst = ei + N_EDGES;
    const float* Ws0 = (const float*)d_in[2];
    const float* Wn0 = (const float*)d_in[3];
    const float* b0  = (const float*)d_in[4];
    const float* Ws1 = (const float*)d_in[5];
    const float* Wn1 = (const float*)d_in[6];
    const float* b1  = (const float*)d_in[7];
    const float* Ws2 = (const float*)d_in[8];
    const float* Wn2 = (const float*)d_in[9];
    const float* b2  = (const float*)d_in[10];

    float* out = (float*)d_out;
    float* out_h3 = out;                                 // [N,16]
    float* out_e0 = out + (size_t)N_NODES * 16;          // [N,64]  pre-relu h1
    float* out_e1 = out + (size_t)N_NODES * (16 + 64);   // [N,64]  pre-relu h2

    char* ws = (char*)d_ws;
    size_t off = 0;
    auto alloc = [&](size_t bytes) -> void* {
        void* p = ws + off;
        off = (off + bytes + 255) & ~(size_t)255;
        return p;
    };
    int* bh          = (int*)alloc((size_t)NBLK * NBUCK * sizeof(int));   // 800 KB
    int* total       = (int*)alloc(NBUCK * sizeof(int));
    int* bucket_base = (int*)alloc((NBUCK + 1) * sizeof(int));
    int* rowptr      = (int*)alloc((N_NODES + 1) * sizeof(int));
    unsigned int* packed = (unsigned int*)alloc(N_EDGES * sizeof(int));   // 6.4 MB
    int* csr         = (int*)alloc(N_EDGES * sizeof(int));                // 6.4 MB
    unsigned int* zb = (unsigned int*)alloc((size_t)N_NODES * 32 * sizeof(unsigned)); // 12.8 MB
    u16* wf0         = (u16*)alloc(16384 * sizeof(u16));  // layer-1 W frags hi/lo (32 KB)
    u16* wf1         = (u16*)alloc(16384 * sizeof(u16));  // layer-2
    u16* wf2         = (u16*)alloc(4096 * sizeof(u16));   // layer-3 (8 KB)
    // layer-3 z (f32 [N,16] = 6.4 MB) aliases `packed` (dead after p4_build)
    float* zbuf3     = (float*)packed;
    (void)ws_size;

    q1_hist<<<NBLK, 512, 0, stream>>>(dst, bh, N_EDGES,
                                      Ws0, Wn0, Ws1, Wn1, Ws2, Wn2, wf0, wf1, wf2);
    q2_colscan<<<NBUCK, 512, 0, stream>>>(bh, total);
    q3_scan<<<1, 512, 0, stream>>>(total, bucket_base, N_EDGES);
    // fused: q4 scatter (blocks 0..511) + layer-1 MFMA (blocks 512..1293)
    f_q4m1<<<NBLK + 782, 512, 0, stream>>>(src, dst, bh, bucket_base, packed, N_EDGES,
                                           feat, wf0, b0, out_e0, zb);
    p4_build<<<NBUCK, 1024, 0, stream>>>(packed, bucket_base, rowptr, csr,
                                         N_NODES, N_EDGES);

    // layer 1 gather
    k_gather64b<<<2048, 256, 0, stream>>>(rowptr, csr, zb, out_e0);
    // layer 2
    k_mfma128s<true><<<(N_NODES + 63) / 64, 256, 0, stream>>>(out_e0, wf1, b1, out_e1, zb);
    k_gather64b<<<2048, 256, 0, stream>>>(rowptr, csr, zb, out_e1);
    // layer 3
    k_mfma32<<<(N_NODES + 63) / 64, 256, 0, stream>>>(out_e1, wf2, b2, out_h3, zbuf3);
    k_gather3<<<2048, 256, 0, stream>>>(rowptr, csr, zbuf3, out_h3, out_h3);
}

// Round 9
// 278.974 us; speedup vs baseline: 4.8738x; 1.0605x over previous
//
#include <hip/hip_runtime.h>
#include <hip/hip_bf16.h>

typedef __hip_bfloat16 bf16;
typedef unsigned short u16;
typedef __attribute__((ext_vector_type(8))) short bf16x8;   // 8 bf16 in 4 VGPRs (MFMA A/B frag)
typedef __attribute__((ext_vector_type(4))) float f32x4;    // MFMA C/D frag

#define N_NODES 100000
#define N_EDGES 1600000
#define NBUCK 391           // ceil(N_NODES/256), bucket = dst >> 8
#define NBLK 512            // edge-chunk blocks for hist/scatter (q1/q2/q4)

static __device__ __forceinline__ u16 f2bf(float x) {
    bf16 h = (bf16)x;
    return *reinterpret_cast<u16*>(&h);
}
static __device__ __forceinline__ float bf2f(u16 b) {
    unsigned u = ((unsigned)b) << 16;
    return __uint_as_float(u);
}

// ================= Weight pre-fragmentation (device fn, folded into q1) =================
// W' = [Ws | Wn] combined, [64 k][2*ncol n], split into bf16 hi/lo:
//   w = wh + wl  (3-pass GEMM ah@wh + al@wh + ah@wl -> f32-grade accuracy).

static __device__ void wprep_one(int id,
                                 const float* Ws0, const float* Wn0,
                                 const float* Ws1, const float* Wn1,
                                 const float* Ws2, const float* Wn2,
                                 u16* wf0, u16* wf1, u16* wf2) {
    const float *Ws, *Wn;
    u16* wf;
    int ncol, nfc;
    if (id < 4096)       { Ws = Ws0; Wn = Wn0; wf = wf0; ncol = 64; nfc = 8; }
    else if (id < 8192)  { id -= 4096; Ws = Ws1; Wn = Wn1; wf = wf1; ncol = 64; nfc = 8; }
    else if (id < 9216)  { id -= 8192; Ws = Ws2; Wn = Wn2; wf = wf2; ncol = 16; nfc = 2; }
    else return;
    int kp = id / (2 * ncol);       // 0..31 k-pair
    int n  = id % (2 * ncol);
    int k  = kp * 2;
    float w0 = (n < ncol) ? Ws[k * ncol + n]       : Wn[k * ncol + (n - ncol)];
    float w1 = (n < ncol) ? Ws[(k + 1) * ncol + n] : Wn[(k + 1) * ncol + (n - ncol)];
    u16 h0 = f2bf(w0), h1 = f2bf(w1);
    u16 l0 = f2bf(w0 - bf2f(h0)), l1 = f2bf(w1 - bf2f(h1));
    int ks = k >> 5, kg = (k >> 3) & 3, j = k & 7;          // j even
    int nf = n >> 4, nl = n & 15;
    int lane = kg * 16 + nl;
    int bhi = ((ks * nfc + nf) * 2 + 0) * 512 + lane * 8 + j;
    int blo = ((ks * nfc + nf) * 2 + 1) * 512 + lane * 8 + j;
    *(unsigned*)&wf[bhi] = (unsigned)h0 | ((unsigned)h1 << 16);
    *(unsigned*)&wf[blo] = (unsigned)l0 | ((unsigned)l1 << 16);
}

// ================= CSR build: deterministic bucket sort (round-5 proven shapes) =================
// Round-2: random 4B global scatter = 16x write amp. Round-4: per-edge conflicted
// LDS atomics ~250cyc. Round-7: 32B quarter-row gather = half-line reads + L2
// thrash. Round-8: q4+m1 fusion neutral but harmless -- kept.

__global__ __launch_bounds__(512) void q1_hist(const int* __restrict__ dst,
                                               int* __restrict__ bh, int nE,
                                               const float* __restrict__ Ws0, const float* __restrict__ Wn0,
                                               const float* __restrict__ Ws1, const float* __restrict__ Wn1,
                                               const float* __restrict__ Ws2, const float* __restrict__ Wn2,
                                               u16* __restrict__ wf0, u16* __restrict__ wf1,
                                               u16* __restrict__ wf2) {
    __shared__ int hist[NBUCK];
    int t = threadIdx.x, b = blockIdx.x;
    if (b < 36 && t < 256)   // folded weight prep (9216 ids)
        wprep_one(b * 256 + t, Ws0, Wn0, Ws1, Wn1, Ws2, Wn2, wf0, wf1, wf2);
    for (int i = t; i < NBUCK; i += 512) hist[i] = 0;
    __syncthreads();
    int chunk = (nE + NBLK - 1) / NBLK;
    int lo = b * chunk, hi = min(nE, lo + chunk);
    for (int e = lo + t; e < hi; e += 512) atomicAdd(&hist[dst[e] >> 8], 1);
    __syncthreads();
    for (int i = t; i < NBUCK; i += 512) bh[b * NBUCK + i] = hist[i];
}

__global__ __launch_bounds__(512) void q2_colscan(int* __restrict__ bh,
                                                  int* __restrict__ total) {
    __shared__ int s[512];
    int i = blockIdx.x;       // bucket
    int b = threadIdx.x;      // chunk-block
    int val = bh[b * NBUCK + i];
    s[b] = val;
    __syncthreads();
    for (int off = 1; off < 512; off <<= 1) {
        int x = (b >= off) ? s[b - off] : 0;
        __syncthreads();
        if (b >= off) s[b] += x;
        __syncthreads();
    }
    bh[b * NBUCK + i] = s[b] - val;        // exclusive over blocks
    if (b == 511) total[i] = s[511];
}

__global__ __launch_bounds__(512) void q3_scan(const int* __restrict__ total,
                                               int* __restrict__ bucket_base, int nE) {
    __shared__ int s[512];
    int t = threadIdx.x;
    int val = (t < NBUCK) ? total[t] : 0;
    s[t] = val;
    __syncthreads();
    for (int off = 1; off < 512; off <<= 1) {
        int x = (t >= off) ? s[t - off] : 0;
        __syncthreads();
        if (t >= off) s[t] += x;
        __syncthreads();
    }
    if (t < NBUCK) bucket_base[t] = s[t] - val;
    if (t == 0) bucket_base[NBUCK] = nE;
}

// ================= MFMA projection body (shared by fused + standalone) =================

template <bool RELU_IN>
static __device__ __forceinline__ void mfma128_body(int rowbase, int lane,
                                                    const float* __restrict__ h,
                                                    const u16* sW,
                                                    const float* __restrict__ bias,
                                                    float* __restrict__ outF,
                                                    unsigned* __restrict__ outZ) {
    int nl = lane & 15, kg = lane >> 4;
    int node = rowbase + nl;
    bool nv = node < N_NODES;
    const float* hp = h + (size_t)node * 64 + kg * 8;

    f32x4 acc[8];
#pragma unroll
    for (int i = 0; i < 8; ++i) acc[i] = (f32x4){0.f, 0.f, 0.f, 0.f};

#pragma unroll
    for (int ks = 0; ks < 2; ++ks) {
        float4 a0, a1;
        if (nv) {
            a0 = *(const float4*)(hp + ks * 32);
            a1 = *(const float4*)(hp + ks * 32 + 4);
        } else {
            a0 = make_float4(0.f, 0.f, 0.f, 0.f);
            a1 = a0;
        }
        float av[8] = {a0.x, a0.y, a0.z, a0.w, a1.x, a1.y, a1.z, a1.w};
        bf16x8 ah, al;
#pragma unroll
        for (int j = 0; j < 8; ++j) {
            float v = av[j];
            if (RELU_IN) v = fmaxf(v, 0.f);
            u16 hb = f2bf(v);
            ah[j] = (short)hb;
            al[j] = (short)f2bf(v - bf2f(hb));
        }
#pragma unroll
        for (int nf = 0; nf < 8; ++nf) {
            bf16x8 wh = *(const bf16x8*)&sW[((ks * 8 + nf) * 2 + 0) * 512 + lane * 8];
            bf16x8 wl = *(const bf16x8*)&sW[((ks * 8 + nf) * 2 + 1) * 512 + lane * 8];
            acc[nf] = __builtin_amdgcn_mfma_f32_16x16x32_bf16(ah, wh, acc[nf], 0, 0, 0);
            acc[nf] = __builtin_amdgcn_mfma_f32_16x16x32_bf16(al, wh, acc[nf], 0, 0, 0);
            acc[nf] = __builtin_amdgcn_mfma_f32_16x16x32_bf16(ah, wl, acc[nf], 0, 0, 0);
        }
    }

    // D layout: col = lane&15, row_in_frag = kg*4 + r  (m89-verified)
#pragma unroll
    for (int nf = 0; nf < 4; ++nf) {            // F half, f32 + bias
        int col = nf * 16 + nl;
        float b = bias[col];
#pragma unroll
        for (int r = 0; r < 4; ++r) {
            int row = rowbase + kg * 4 + r;
            if (row < N_NODES) outF[(size_t)row * 64 + col] = acc[nf][r] + b;
        }
    }
#pragma unroll
    for (int nf = 4; nf < 8; ++nf) {            // Z half, pack bf16 pairs via shfl
        int zc = nf * 16 + nl - 64;
#pragma unroll
        for (int r = 0; r < 4; ++r) {
            float v = acc[nf][r];
            float p = __shfl_xor(v, 1);         // partner col (nl^1), same row
            int row = rowbase + kg * 4 + r;
            if (!(nl & 1) && row < N_NODES)
                outZ[(size_t)row * 32 + (zc >> 1)] = (unsigned)f2bf(v) | ((unsigned)f2bf(p) << 16);
        }
    }
}

// ================= Fused q4_scatter + layer-1 MFMA =================

__global__ __launch_bounds__(512) void f_q4m1(const int* __restrict__ src,
                                              const int* __restrict__ dst,
                                              const int* __restrict__ bh,
                                              const int* __restrict__ bucket_base,
                                              unsigned int* __restrict__ packed, int nE,
                                              const float* __restrict__ h,
                                              const u16* __restrict__ wf,
                                              const float* __restrict__ bias,
                                              float* __restrict__ outF,
                                              unsigned* __restrict__ outZ) {
    __shared__ uint4 smem4[2048];   // 32 KB union
    int t = threadIdx.x;
    if (blockIdx.x < NBLK) {
        // ---- q4 branch (round-5 verbatim) ----
        int* cur = (int*)smem4;
        int b = blockIdx.x;
        for (int i = t; i < NBUCK; i += 512)
            cur[i] = bucket_base[i] + bh[b * NBUCK + i];
        __syncthreads();
        int chunk = (nE + NBLK - 1) / NBLK;
        int lo = b * chunk, hi = min(nE, lo + chunk);
        for (int e = lo + t; e < hi; e += 512) {
            int d = dst[e];
            int pos = atomicAdd(&cur[d >> 8], 1);
            packed[pos] = ((unsigned int)(d & 255) << 17) | (unsigned int)src[e];
        }
    } else {
        // ---- layer-1 MFMA branch ----
        u16* sW = (u16*)smem4;
        const uint4* g = (const uint4*)wf;
#pragma unroll
        for (int i = 0; i < 4; ++i)             // 4 x 512 x 16B = 32 KB
            smem4[t + i * 512] = g[t + i * 512];
        __syncthreads();
        int lane = t & 63, wid = t >> 6;
        int rowbase = (blockIdx.x - NBLK) * 128 + wid * 16;
        mfma128_body<false>(rowbase, lane, h, sW, bias, outF, outZ);
    }
}

__global__ __launch_bounds__(1024) void p4_build(const unsigned int* __restrict__ packed,
                                                 const int* __restrict__ bucket_base,
                                                 int* __restrict__ rowptr,
                                                 int* __restrict__ csr, int nN, int nE) {
    __shared__ int cnt[256];
    __shared__ int s[256];
    __shared__ int curs[256];
    int b = blockIdx.x;
    int t = threadIdx.x;
    int node0 = b << 8;
    int ebase = bucket_base[b];
    int eend  = bucket_base[b + 1];

    if (t < 256) cnt[t] = 0;
    __syncthreads();
    for (int e = ebase + t; e < eend; e += 1024)
        atomicAdd(&cnt[packed[e] >> 17], 1);
    __syncthreads();
    int val = (t < 256) ? cnt[t] : 0;
    if (t < 256) s[t] = val;
    __syncthreads();
    for (int off = 1; off < 256; off <<= 1) {
        int x = (t < 256 && t >= off) ? s[t - off] : 0;
        __syncthreads();
        if (t < 256 && t >= off) s[t] += x;
        __syncthreads();
    }
    if (t < 256) {
        int excl = s[t] - val;
        int node = node0 + t;
        if (node < nN) rowptr[node] = ebase + excl;
        curs[t] = ebase + excl;
    }
    if (b == gridDim.x - 1 && t == 0) rowptr[nN] = nE;
    __syncthreads();
    for (int e = ebase + t; e < eend; e += 1024) {
        unsigned int p = packed[e];
        int d = p >> 17;
        int pos = atomicAdd(&curs[d], 1);
        csr[pos] = (int)(p & 0x1FFFFu);
    }
}

// ================= Standalone MFMA GEMM (layer 2) =================

template <bool RELU_IN>
__global__ __launch_bounds__(256) void k_mfma128s(const float* __restrict__ h,
                                                  const u16* __restrict__ wf,
                                                  const float* __restrict__ bias,
                                                  float* __restrict__ outF,
                                                  unsigned* __restrict__ outZ) {
    __shared__ u16 sW[16384];   // 32 KB
    int t = threadIdx.x;
    {
        const uint4* g = (const uint4*)wf;
        uint4* s = (uint4*)sW;
#pragma unroll
        for (int i = 0; i < 8; ++i) s[t + i * 256] = g[t + i * 256];
    }
    __syncthreads();
    int lane = t & 63, wid = t >> 6;
    mfma128_body<RELU_IN>(blockIdx.x * 64 + wid * 16, lane, h, sW, bias, outF, outZ);
}

// ================= MFMA projection, layer 3 (round-5 verbatim) =================

__global__ __launch_bounds__(256) void k_mfma32(const float* __restrict__ h,
                                                const u16* __restrict__ wf,
                                                const float* __restrict__ bias,
                                                float* __restrict__ wbuf,
                                                float* __restrict__ zbuf) {
    __shared__ u16 sW[4096];    // 8 KB
    int t = threadIdx.x;
    {
        const uint4* g = (const uint4*)wf;
        uint4* s = (uint4*)sW;
        s[t] = g[t];
        s[t + 256] = g[t + 256];
    }
    __syncthreads();

    int lane = t & 63, wid = t >> 6;
    int nl = lane & 15, kg = lane >> 4;
    int rowbase = blockIdx.x * 64 + wid * 16;
    int node = rowbase + nl;
    bool nv = node < N_NODES;
    const float* hp = h + (size_t)node * 64 + kg * 8;

    f32x4 acc[2];
    acc[0] = (f32x4){0.f, 0.f, 0.f, 0.f};
    acc[1] = acc[0];

#pragma unroll
    for (int ks = 0; ks < 2; ++ks) {
        float4 a0, a1;
        if (nv) {
            a0 = *(const float4*)(hp + ks * 32);
            a1 = *(const float4*)(hp + ks * 32 + 4);
        } else {
            a0 = make_float4(0.f, 0.f, 0.f, 0.f);
            a1 = a0;
        }
        float av[8] = {a0.x, a0.y, a0.z, a0.w, a1.x, a1.y, a1.z, a1.w};
        bf16x8 ah, al;
#pragma unroll
        for (int j = 0; j < 8; ++j) {
            float v = fmaxf(av[j], 0.f);        // layer-3 input is relu(h2)
            u16 hb = f2bf(v);
            ah[j] = (short)hb;
            al[j] = (short)f2bf(v - bf2f(hb));
        }
#pragma unroll
        for (int nf = 0; nf < 2; ++nf) {
            bf16x8 wh = *(const bf16x8*)&sW[((ks * 2 + nf) * 2 + 0) * 512 + lane * 8];
            bf16x8 wl = *(const bf16x8*)&sW[((ks * 2 + nf) * 2 + 1) * 512 + lane * 8];
            acc[nf] = __builtin_amdgcn_mfma_f32_16x16x32_bf16(ah, wh, acc[nf], 0, 0, 0);
            acc[nf] = __builtin_amdgcn_mfma_f32_16x16x32_bf16(al, wh, acc[nf], 0, 0, 0);
            acc[nf] = __builtin_amdgcn_mfma_f32_16x16x32_bf16(ah, wl, acc[nf], 0, 0, 0);
        }
    }

    float b = bias[nl];
#pragma unroll
    for (int r = 0; r < 4; ++r) {
        int row = rowbase + kg * 4 + r;
        if (row < N_NODES) {
            wbuf[(size_t)row * 16 + nl] = acc[0][r] + b;   // self + bias
            zbuf[(size_t)row * 16 + nl] = acc[1][r];       // neigh projection
        }
    }
}

// ===== Gather (layers 1/2, bf16 z): out[v] += segmean(z[src]) =====
// Round-9: vectorized to uint4 (16 B/lane): 8 lanes cover a 128B z-row ->
// 8 edges per wave-load (vs 2). Load instructions per 64-edge chunk: 32 -> 8.
// Same bytes, same math; targets the issue/latency component. Register
// accumulation (round-4 lesson: no per-edge LDS atomics).

__global__ __launch_bounds__(256, 8) void k_gather64b(const int* __restrict__ rowptr,
                                                      const int* __restrict__ csr,
                                                      const uint4* __restrict__ z,   // [N][8] uint4
                                                      float* __restrict__ out) {
    int t = threadIdx.x;
    int w = t >> 6, lane = t & 63;
    int sub = lane >> 3;      // edge slot 0..7
    int f = lane & 7;         // uint4 index within 128B row

    for (int v = blockIdx.x * 4 + w; v < N_NODES; v += gridDim.x * 4) {
        int beg = rowptr[v];
        int end = rowptr[v + 1];
        float a0 = 0.f, a1 = 0.f, a2 = 0.f, a3 = 0.f;
        float a4 = 0.f, a5 = 0.f, a6 = 0.f, a7 = 0.f;

#define ACC8(d) do {                                                     \
        a0 += __uint_as_float((d).x << 16); a1 += __uint_as_float((d).x & 0xffff0000u); \
        a2 += __uint_as_float((d).y << 16); a3 += __uint_as_float((d).y & 0xffff0000u); \
        a4 += __uint_as_float((d).z << 16); a5 += __uint_as_float((d).z & 0xffff0000u); \
        a6 += __uint_as_float((d).w << 16); a7 += __uint_as_float((d).w & 0xffff0000u); } while (0)

        for (int e0 = beg; e0 < end; e0 += 64) {
            int n = end - e0; if (n > 64) n = 64;
            int ids = (e0 + lane < end) ? csr[e0 + lane] : 0;
            int g8 = n >> 3;
            int i = 0;
            for (; i + 2 <= g8; i += 2) {
                int r0 = __shfl(ids, 8 * i + sub);
                int r1 = __shfl(ids, 8 * i + 8 + sub);
                uint4 d0 = z[(size_t)r0 * 8 + f];
                uint4 d1 = z[(size_t)r1 * 8 + f];
                ACC8(d0);
                ACC8(d1);
            }
            if (i < g8) {
                int r = __shfl(ids, 8 * i + sub);
                uint4 d = z[(size_t)r * 8 + f];
                ACC8(d);
            }
            int rem = n & 7;
            if (rem) {
                int e = (n & ~7) + sub;
                int r = __shfl(ids, (e < n) ? e : (n - 1));
                if (e < n) {
                    uint4 d = z[(size_t)r * 8 + f];
                    ACC8(d);
                }
            }
        }
#undef ACC8

        a0 += __shfl_xor(a0, 8);  a1 += __shfl_xor(a1, 8);
        a2 += __shfl_xor(a2, 8);  a3 += __shfl_xor(a3, 8);
        a4 += __shfl_xor(a4, 8);  a5 += __shfl_xor(a5, 8);
        a6 += __shfl_xor(a6, 8);  a7 += __shfl_xor(a7, 8);
        a0 += __shfl_xor(a0, 16); a1 += __shfl_xor(a1, 16);
        a2 += __shfl_xor(a2, 16); a3 += __shfl_xor(a3, 16);
        a4 += __shfl_xor(a4, 16); a5 += __shfl_xor(a5, 16);
        a6 += __shfl_xor(a6, 16); a7 += __shfl_xor(a7, 16);
        a0 += __shfl_xor(a0, 32); a1 += __shfl_xor(a1, 32);
        a2 += __shfl_xor(a2, 32); a3 += __shfl_xor(a3, 32);
        a4 += __shfl_xor(a4, 32); a5 += __shfl_xor(a5, 32);
        a6 += __shfl_xor(a6, 32); a7 += __shfl_xor(a7, 32);

        if (sub == 0) {
            float inv = 1.f / fmaxf((float)(end - beg), 1.f);
            float4* op = (float4*)(out + (size_t)v * 64 + f * 8);
            float4 c0 = op[0], c1 = op[1];
            c0.x += a0 * inv; c0.y += a1 * inv; c0.z += a2 * inv; c0.w += a3 * inv;
            c1.x += a4 * inv; c1.y += a5 * inv; c1.z += a6 * inv; c1.w += a7 * inv;
            op[0] = c0; op[1] = c1;
        }
    }
}

// ===== Layer-3 gather: float4 loads, 4 lanes per 64B row -> 16 edges/wave-load =====

__global__ __launch_bounds__(256, 8) void k_gather3(const int* __restrict__ rowptr,
                                                    const int* __restrict__ csr,
                                                    const float4* __restrict__ zbuf,  // [N][4] float4
                                                    const float* __restrict__ wbuf,
                                                    float* __restrict__ out) {
    int t = threadIdx.x;
    int w = t >> 6, lane = t & 63;
    int sub = lane >> 2;      // edge slot 0..15
    int f = lane & 3;         // float4 index within 64B row

    for (int v = blockIdx.x * 4 + w; v < N_NODES; v += gridDim.x * 4) {
        int beg = rowptr[v];
        int end = rowptr[v + 1];
        float a0 = 0.f, a1 = 0.f, a2 = 0.f, a3 = 0.f;

        for (int e0 = beg; e0 < end; e0 += 64) {
            int n = end - e0; if (n > 64) n = 64;
            int ids = (e0 + lane < end) ? csr[e0 + lane] : 0;
            int g16 = n >> 4;
            int i = 0;
            for (; i + 2 <= g16; i += 2) {
                int r0 = __shfl(ids, 16 * i + sub);
                int r1 = __shfl(ids, 16 * i + 16 + sub);
                float4 d0 = zbuf[(size_t)r0 * 4 + f];
                float4 d1 = zbuf[(size_t)r1 * 4 + f];
                a0 += d0.x + d1.x; a1 += d0.y + d1.y;
                a2 += d0.z + d1.z; a3 += d0.w + d1.w;
            }
            if (i < g16) {
                int r = __shfl(ids, 16 * i + sub);
                float4 d = zbuf[(size_t)r * 4 + f];
                a0 += d.x; a1 += d.y; a2 += d.z; a3 += d.w;
            }
            int rem = n & 15;
            if (rem) {
                int e = (n & ~15) + sub;
                int r = __shfl(ids, (e < n) ? e : (n - 1));
                if (e < n) {
                    float4 d = zbuf[(size_t)r * 4 + f];
                    a0 += d.x; a1 += d.y; a2 += d.z; a3 += d.w;
                }
            }
        }

        a0 += __shfl_xor(a0, 4);  a1 += __shfl_xor(a1, 4);
        a2 += __shfl_xor(a2, 4);  a3 += __shfl_xor(a3, 4);
        a0 += __shfl_xor(a0, 8);  a1 += __shfl_xor(a1, 8);
        a2 += __shfl_xor(a2, 8);  a3 += __shfl_xor(a3, 8);
        a0 += __shfl_xor(a0, 16); a1 += __shfl_xor(a1, 16);
        a2 += __shfl_xor(a2, 16); a3 += __shfl_xor(a3, 16);
        a0 += __shfl_xor(a0, 32); a1 += __shfl_xor(a1, 32);
        a2 += __shfl_xor(a2, 32); a3 += __shfl_xor(a3, 32);

        if (sub == 0) {
            float inv = 1.f / fmaxf((float)(end - beg), 1.f);
            float4 wv = ((const float4*)(wbuf + (size_t)v * 16))[f];
            float4 o;
            o.x = wv.x + a0 * inv; o.y = wv.y + a1 * inv;
            o.z = wv.z + a2 * inv; o.w = wv.w + a3 * inv;
            ((float4*)(out + (size_t)v * 16))[f] = o;
        }
    }
}

// ---------------- launch ----------------

extern "C" void kernel_launch(void* const* d_in, const int* in_sizes, int n_in,
                              void* d_out, int out_size, void* d_ws, size_t ws_size,
                              hipStream_t stream) {
    const float* feat = (const float*)d_in[0];
    const int* ei = (const int*)d_in[1];
    const int* src = ei;
    const int* dst = ei + N_EDGES;
    const float* Ws0 = (const float*)d_in[2];
    const float* Wn0 = (const float*)d_in[3];
    const float* b0  = (const float*)d_in[4];
    const float* Ws1 = (const float*)d_in[5];
    const float* Wn1 = (const float*)d_in[6];
    const float* b1  = (const float*)d_in[7];
    const float* Ws2 = (const float*)d_in[8];
    const float* Wn2 = (const float*)d_in[9];
    const float* b2  = (const float*)d_in[10];

    float* out = (float*)d_out;
    float* out_h3 = out;                                 // [N,16]
    float* out_e0 = out + (size_t)N_NODES * 16;          // [N,64]  pre-relu h1
    float* out_e1 = out + (size_t)N_NODES * (16 + 64);   // [N,64]  pre-relu h2

    char* ws = (char*)d_ws;
    size_t off = 0;
    auto alloc = [&](size_t bytes) -> void* {
        void* p = ws + off;
        off = (off + bytes + 255) & ~(size_t)255;
        return p;
    };
    int* bh          = (int*)alloc((size_t)NBLK * NBUCK * sizeof(int));   // 800 KB
    int* total       = (int*)alloc(NBUCK * sizeof(int));
    int* bucket_base = (int*)alloc((NBUCK + 1) * sizeof(int));
    int* rowptr      = (int*)alloc((N_NODES + 1) * sizeof(int));
    unsigned int* packed = (unsigned int*)alloc(N_EDGES * sizeof(int));   // 6.4 MB
    int* csr         = (int*)alloc(N_EDGES * sizeof(int));                // 6.4 MB
    unsigned int* zb = (unsigned int*)alloc((size_t)N_NODES * 32 * sizeof(unsigned)); // 12.8 MB
    u16* wf0         = (u16*)alloc(16384 * sizeof(u16));  // layer-1 W frags hi/lo (32 KB)
    u16* wf1         = (u16*)alloc(16384 * sizeof(u16));  // layer-2
    u16* wf2         = (u16*)alloc(4096 * sizeof(u16));   // layer-3 (8 KB)
    // layer-3 z (f32 [N,16] = 6.4 MB) aliases `packed` (dead after p4_build)
    float* zbuf3     = (float*)packed;
    (void)ws_size;

    q1_hist<<<NBLK, 512, 0, stream>>>(dst, bh, N_EDGES,
                                      Ws0, Wn0, Ws1, Wn1, Ws2, Wn2, wf0, wf1, wf2);
    q2_colscan<<<NBUCK, 512, 0, stream>>>(bh, total);
    q3_scan<<<1, 512, 0, stream>>>(total, bucket_base, N_EDGES);
    // fused: q4 scatter (blocks 0..511) + layer-1 MFMA (blocks 512..1293)
    f_q4m1<<<NBLK + 782, 512, 0, stream>>>(src, dst, bh, bucket_base, packed, N_EDGES,
                                           feat, wf0, b0, out_e0, zb);
    p4_build<<<NBUCK, 1024, 0, stream>>>(packed, bucket_base, rowptr, csr,
                                         N_NODES, N_EDGES);

    // layer 1 gather
    k_gather64b<<<2048, 256, 0, stream>>>(rowptr, csr, (const uint4*)zb, out_e0);
    // layer 2
    k_mfma128s<true><<<(N_NODES + 63) / 64, 256, 0, stream>>>(out_e0, wf1, b1, out_e1, zb);
    k_gather64b<<<2048, 256, 0, stream>>>(rowptr, csr, (const uint4*)zb, out_e1);
    // layer 3
    k_mfma32<<<(N_NODES + 63) / 64, 256, 0, stream>>>(out_e1, wf2, b2, out_h3, zbuf3);
    k_gather3<<<2048, 256, 0, stream>>>(rowptr, csr, (const float4*)zbuf3, out_h3, out_h3);
}